// Round 1
// baseline (121065.271 us; speedup 1.0000x reference)
//
#include <hip/hip_runtime.h>
#include <cstdint>

typedef unsigned int uint32;

#define SEQn 1024
#define Bn 256
#define INn 256
#define Hn 512
#define SWn 128
#define SDn 64

typedef float f32x4 __attribute__((ext_vector_type(4)));
typedef short s16x8 __attribute__((ext_vector_type(8)));

__device__ __forceinline__ unsigned short f2bf(float f) {
  union { __bf16 b; unsigned short u; } cv;
  cv.b = (__bf16)f;
  return cv.u;
}

__device__ __forceinline__ float sigm(float x) { return 1.0f / (1.0f + expf(-x)); }

__device__ __forceinline__ s16x8 pack8(f32x4 a, f32x4 b) {
  s16x8 r;
  r[0] = (short)f2bf(a[0]); r[1] = (short)f2bf(a[1]);
  r[2] = (short)f2bf(a[2]); r[3] = (short)f2bf(a[3]);
  r[4] = (short)f2bf(b[0]); r[5] = (short)f2bf(b[1]);
  r[6] = (short)f2bf(b[2]); r[7] = (short)f2bf(b[3]);
  return r;
}

// ---- LDS layout (bytes) ----
// W slice:   [64 rows][904 bf16]  row stride 1808  (cols 0..511 = W_hh, 512..767 = W_ih x-part, 768..895 = W_ih s0-part)
// misc:      [8 rows][520 bf16]   row stride 1040  (rows 0..3 = D_w slice, 4..6 = A_w, 7 = zeros)
// xh:        [32 rows][520 bf16]  row stride 1040  (staged h; reused as misc-partials [0..8KB] and gate-exchange [8..16KB])
#define OFF_W    0
#define OFF_MISC 115712
#define OFF_XH   124032
#define OFF_BIAS 157312
#define OFF_DB   157568
#define OFF_AB   157584
#define OFF_ALOG 157600
#define OFF_CTL  157984
#define LDS_SZ   158368

__global__ void __launch_bounds__(256, 1) init_kernel(
    const float* __restrict__ h0, const float* __restrict__ c0,
    const float* __restrict__ st0,
    unsigned short* __restrict__ ws_h, float* __restrict__ ws_c,
    float* __restrict__ stk0, uint32* __restrict__ bar) {
  size_t idx = (size_t)blockIdx.x * 256 + threadIdx.x;
  if (idx < (size_t)Bn * Hn) { ws_h[idx] = f2bf(h0[idx]); ws_c[idx] = c0[idx]; }
  if (idx < (size_t)Bn * SDn * SWn) stk0[idx] = st0[idx];
  if (idx < 512) bar[idx] = 0;
}

__device__ __forceinline__ void group_barrier(uint32* ctr, uint32 target) {
  __threadfence();            // agent-scope release of this block's prior writes
  __syncthreads();
  if (threadIdx.x == 0) {
    __hip_atomic_fetch_add(ctr, 1u, __ATOMIC_RELAXED, __HIP_MEMORY_SCOPE_AGENT);
    while (__hip_atomic_load(ctr, __ATOMIC_RELAXED, __HIP_MEMORY_SCOPE_AGENT) < target)
      __builtin_amdgcn_s_sleep(2);
  }
  __syncthreads();
  __threadfence();            // acquire: invalidate stale cache lines before reading peer data
}

__global__ void __launch_bounds__(256, 1) rnn_kernel(
    const float* __restrict__ x,
    const float* __restrict__ A_w, const float* __restrict__ A_b,
    const float* __restrict__ D_w, const float* __restrict__ D_b,
    const float* __restrict__ W_ih, const float* __restrict__ W_hh,
    const float* __restrict__ b_ih, const float* __restrict__ b_hh,
    float* __restrict__ out,
    unsigned short* __restrict__ ws_h, float* __restrict__ ws_c,
    float* __restrict__ ws_d, uint32* __restrict__ bar,
    float* __restrict__ stkA, float* __restrict__ stkB) {
  __shared__ __align__(16) char LDS_[LDS_SZ];
  const int tid = threadIdx.x;
  const int s = blockIdx.x & 31;   // gate-slice: units s*16..s*16+15, D rows s*4..s*4+3
  const int j = blockIdx.x >> 5;   // batch group: batches j*32..j*32+31
  const int b0 = j * 32;

  float* biasL = (float*)(LDS_ + OFF_BIAS);
  float* DbL   = (float*)(LDS_ + OFF_DB);
  float* AbL   = (float*)(LDS_ + OFF_AB);
  float* AlogL = (float*)(LDS_ + OFF_ALOG);
  float* CtlL  = (float*)(LDS_ + OFF_CTL);

  // ---- one-time: stage bf16 weight slices into LDS ----
  {
    int n = tid >> 2, q = tid & 3;                 // 64 rows x 4 col-quarters
    int grow = (n >> 4) * Hn + s * 16 + (n & 15);  // interleaved: 16 units per gate
    const float* whh = W_hh + (size_t)grow * Hn;
    const float* wih = W_ih + (size_t)grow * (INn + SWn);
    unsigned short* dst = (unsigned short*)(LDS_ + OFF_W + n * 1808);
    for (int c4 = 0; c4 < 56; ++c4) {
      int c = q * 224 + c4 * 4;
      f32x4 v = (c < Hn) ? *(const f32x4*)(whh + c) : *(const f32x4*)(wih + (c - Hn));
      dst[c + 0] = f2bf(v[0]); dst[c + 1] = f2bf(v[1]);
      dst[c + 2] = f2bf(v[2]); dst[c + 3] = f2bf(v[3]);
    }
    int r = tid >> 5, k0 = (tid & 31) * 16;        // misc rows
    unsigned short* md = (unsigned short*)(LDS_ + OFF_MISC + r * 1040);
    const float* src = (r < 4) ? (D_w + (size_t)(s * 4 + r) * Hn)
                               : (r < 7 ? (A_w + (size_t)(r - 4) * Hn) : nullptr);
    for (int k = k0; k < k0 + 16; ++k) md[k] = src ? f2bf(src[k]) : (unsigned short)0;
    if (tid < 64) {
      int grow2 = (tid >> 4) * Hn + s * 16 + (tid & 15);
      biasL[tid] = b_ih[grow2] + b_hh[grow2];
    }
    if (tid < 4) DbL[tid] = D_b[s * 4 + tid];
    if (tid < 3) AbL[tid] = A_b[tid];
  }
  __syncthreads();

  uint32* gbar = bar + j * 64;
  const int w = tid >> 6, l = tid & 63;
  const int lr = l & 15, lk = l >> 4;
  const char* WL  = LDS_ + OFF_W + (w * 16 + lr) * 1808;
  const char* XH0 = LDS_ + OFF_XH + lr * 1040;
  const char* XH1 = LDS_ + OFF_XH + (16 + lr) * 1040;

  for (int t = 0; t < SEQn; ++t) {
    // ---- stage h (bf16) into LDS ----
    {
      int b = tid >> 3, cko = (tid & 7) * 64;
      const uint4* src = (const uint4*)(ws_h + (size_t)(b0 + b) * Hn + cko);
      uint4* dst = (uint4*)(LDS_ + OFF_XH + b * 1040 + cko * 2);
#pragma unroll
      for (int i = 0; i < 8; ++i) dst[i] = src[i];
    }
    __syncthreads();

    f32x4 acc0 = {0.f, 0.f, 0.f, 0.f}, acc1 = acc0, am0 = acc0, am1 = acc0;

    // ---- P1: gates += h @ W_hh^T  (K=512) ----
#pragma unroll
    for (int ki = 0; ki < 16; ++ki) {
      int kb = ki * 64 + lk * 16;
      s16x8 a0 = *(const s16x8*)(XH0 + kb);
      s16x8 a1 = *(const s16x8*)(XH1 + kb);
      s16x8 bb = *(const s16x8*)(WL + kb);
      acc0 = __builtin_amdgcn_mfma_f32_16x16x32_bf16(a0, bb, acc0, 0, 0, 0);
      acc1 = __builtin_amdgcn_mfma_f32_16x16x32_bf16(a1, bb, acc1, 0, 0, 0);
    }
    // ---- P1: gates += x_t @ W_ih_x^T  (K=256, x loaded fp32 from global, cvt bf16) ----
    const float* xt  = x + (size_t)t * Bn * INn;
    const float* xr0 = xt + (size_t)(b0 + lr) * INn;
    const float* xr1 = xt + (size_t)(b0 + 16 + lr) * INn;
#pragma unroll
    for (int kx = 0; kx < 8; ++kx) {
      int k = kx * 32 + lk * 8;
      f32x4 p0 = *(const f32x4*)(xr0 + k), p1 = *(const f32x4*)(xr0 + k + 4);
      f32x4 q0 = *(const f32x4*)(xr1 + k), q1 = *(const f32x4*)(xr1 + k + 4);
      s16x8 a0 = pack8(p0, p1);
      s16x8 a1 = pack8(q0, q1);
      s16x8 bb = *(const s16x8*)(WL + 1024 + kx * 64 + lk * 16);
      acc0 = __builtin_amdgcn_mfma_f32_16x16x32_bf16(a0, bb, acc0, 0, 0, 0);
      acc1 = __builtin_amdgcn_mfma_f32_16x16x32_bf16(a1, bb, acc1, 0, 0, 0);
    }
    // ---- P1: misc tile (D rows + A rows), K split across waves ----
#pragma unroll
    for (int km = 0; km < 4; ++km) {
      int kb = w * 256 + km * 64 + lk * 16;
      s16x8 a0 = *(const s16x8*)(XH0 + kb);
      s16x8 a1 = *(const s16x8*)(XH1 + kb);
      s16x8 bm = *(const s16x8*)(LDS_ + OFF_MISC + (lr & 7) * 1040 + kb);
      am0 = __builtin_amdgcn_mfma_f32_16x16x32_bf16(a0, bm, am0, 0, 0, 0);
      am1 = __builtin_amdgcn_mfma_f32_16x16x32_bf16(a1, bm, am1, 0, 0, 0);
    }
    __syncthreads();
    // misc partial exchange + reduce (d rows -> ws_d, A logits -> softmax -> CtlL)
    float* mp = (float*)(LDS_ + OFF_XH);
    *(f32x4*)(mp + (w * 2 + 0) * 256 + lr * 16 + lk * 4) = am0;
    *(f32x4*)(mp + (w * 2 + 1) * 256 + lr * 16 + lk * 4) = am1;
    __syncthreads();
    {
      int mt = tid >> 7, n = (tid >> 4) & 7, m = tid & 15;
      float v = mp[(0 + mt) * 256 + n * 16 + m] + mp[(2 + mt) * 256 + n * 16 + m]
              + mp[(4 + mt) * 256 + n * 16 + m] + mp[(6 + mt) * 256 + n * 16 + m];
      int b = mt * 16 + m;
      if (n < 4) {
        ws_d[(size_t)(b0 + b) * SWn + s * 4 + n] = tanhf(v + DbL[n]);
      } else if (n < 7) {
        AlogL[b * 3 + (n - 4)] = v + AbL[n - 4];
      }
    }
    __syncthreads();
    if (tid < 32) {
      float l0 = AlogL[tid * 3], l1 = AlogL[tid * 3 + 1], l2 = AlogL[tid * 3 + 2];
      float mx = fmaxf(l0, fmaxf(l1, l2));
      float e0 = expf(l0 - mx), e1 = expf(l1 - mx), e2 = expf(l2 - mx);
      float inv = 1.f / (e0 + e1 + e2);
      CtlL[tid * 3] = e0 * inv; CtlL[tid * 3 + 1] = e1 * inv; CtlL[tid * 3 + 2] = e2 * inv;
    }
    group_barrier(gbar, 32u * (uint32)(2 * t + 1));   // publish d (controls are redundant/per-block)

    const float* stk_old = (t & 1) ? stkB : stkA;
    float*       stk_new = (t & 1) ? stkA : stkB;

    // ---- P2: gates += s0 @ W_ih_s^T (s0 rebuilt per-lane from old stack rows 0/1 + d) ----
#pragma unroll
    for (int ks = 0; ks < 4; ++ks) {
      int k = ks * 32 + lk * 8;
      s16x8 bb = *(const s16x8*)(WL + 1536 + ks * 64 + lk * 16);
      {
        size_t bg = (size_t)(b0 + lr);
        float cp = CtlL[lr * 3], cq = CtlL[lr * 3 + 1], cn = CtlL[lr * 3 + 2];
        const float* dp = ws_d + bg * SWn + k;
        const float* o0 = stk_old + (bg * SDn + 0) * SWn + k;
        const float* o1 = stk_old + (bg * SDn + 1) * SWn + k;
        f32x4 d0 = *(const f32x4*)dp,        d1 = *(const f32x4*)(dp + 4);
        f32x4 t0 = *(const f32x4*)o0,        t1 = *(const f32x4*)(o0 + 4);
        f32x4 u0 = *(const f32x4*)o1,        u1 = *(const f32x4*)(o1 + 4);
        f32x4 y0, y1;
        y0[0] = cn * t0[0] + cp * d0[0] + cq * u0[0];
        y0[1] = cn * t0[1] + cp * d0[1] + cq * u0[1];
        y0[2] = cn * t0[2] + cp * d0[2] + cq * u0[2];
        y0[3] = cn * t0[3] + cp * d0[3] + cq * u0[3];
        y1[0] = cn * t1[0] + cp * d1[0] + cq * u1[0];
        y1[1] = cn * t1[1] + cp * d1[1] + cq * u1[1];
        y1[2] = cn * t1[2] + cp * d1[2] + cq * u1[2];
        y1[3] = cn * t1[3] + cp * d1[3] + cq * u1[3];
        s16x8 a0 = pack8(y0, y1);
        acc0 = __builtin_amdgcn_mfma_f32_16x16x32_bf16(a0, bb, acc0, 0, 0, 0);
      }
      {
        size_t bg = (size_t)(b0 + 16 + lr);
        int bl = 16 + lr;
        float cp = CtlL[bl * 3], cq = CtlL[bl * 3 + 1], cn = CtlL[bl * 3 + 2];
        const float* dp = ws_d + bg * SWn + k;
        const float* o0 = stk_old + (bg * SDn + 0) * SWn + k;
        const float* o1 = stk_old + (bg * SDn + 1) * SWn + k;
        f32x4 d0 = *(const f32x4*)dp,        d1 = *(const f32x4*)(dp + 4);
        f32x4 t0 = *(const f32x4*)o0,        t1 = *(const f32x4*)(o0 + 4);
        f32x4 u0 = *(const f32x4*)o1,        u1 = *(const f32x4*)(o1 + 4);
        f32x4 y0, y1;
        y0[0] = cn * t0[0] + cp * d0[0] + cq * u0[0];
        y0[1] = cn * t0[1] + cp * d0[1] + cq * u0[1];
        y0[2] = cn * t0[2] + cp * d0[2] + cq * u0[2];
        y0[3] = cn * t0[3] + cp * d0[3] + cq * u0[3];
        y1[0] = cn * t1[0] + cp * d1[0] + cq * u1[0];
        y1[1] = cn * t1[1] + cp * d1[1] + cq * u1[1];
        y1[2] = cn * t1[2] + cp * d1[2] + cq * u1[2];
        y1[3] = cn * t1[3] + cp * d1[3] + cq * u1[3];
        s16x8 a1 = pack8(y0, y1);
        acc1 = __builtin_amdgcn_mfma_f32_16x16x32_bf16(a1, bb, acc1, 0, 0, 0);
      }
    }

    // ---- gate exchange (wave w holds gate w) ----
    float* ge = (float*)(LDS_ + OFF_XH + 8192);
    *(f32x4*)(ge + (w * 16 + lr) * 32 + lk * 4)      = acc0;
    *(f32x4*)(ge + (w * 16 + lr) * 32 + 16 + lk * 4) = acc1;
    __syncthreads();

    // ---- LSTM pointwise update for this block's 16 units x 32 batches ----
#pragma unroll
    for (int e = 0; e < 2; ++e) {
      int p = tid + e * 256;
      int ul = p & 15, b = p >> 4;
      size_t bg = (size_t)(b0 + b);
      int u = s * 16 + ul;
      float iv = ge[(ul) * 32 + b]      + biasL[ul];
      float fv = ge[(16 + ul) * 32 + b] + biasL[16 + ul];
      float gv = ge[(32 + ul) * 32 + b] + biasL[32 + ul];
      float ov = ge[(48 + ul) * 32 + b] + biasL[48 + ul];
      float co = ws_c[bg * Hn + u];
      float cnew = sigm(fv) * co + sigm(iv) * tanhf(gv);
      float hv = sigm(ov) * tanhf(cnew);
      ws_c[bg * Hn + u] = cnew;
      out[((size_t)t * Bn + bg) * Hn + u] = hv;
      ws_h[bg * Hn + u] = f2bf(hv);
      if (t == SEQn - 1) {
        out[(size_t)SEQn * Bn * Hn + bg * Hn + u] = hv;
        out[(size_t)SEQn * Bn * Hn + (size_t)Bn * Hn + bg * Hn + u] = cnew;
      }
    }

    // ---- stack update: this block owns rows s*2, s*2+1 for all 32 group batches ----
#pragma unroll 4
    for (int i = 0; i < 32; ++i) {
      int f = i * 256 + tid;
      int k = f & 127, bi = (f >> 7) & 31, rr = f >> 12;
      int r = s * 2 + rr;
      size_t bg = (size_t)(b0 + bi);
      size_t base = (bg * SDn + r) * SWn + k;
      float oc = stk_old[base];
      float om = (r == 0) ? ws_d[bg * SWn + k] : stk_old[base - SWn];
      float op = (r == SDn - 1) ? 0.f : stk_old[base + SWn];
      float cp = CtlL[bi * 3], cq = CtlL[bi * 3 + 1], cn = CtlL[bi * 3 + 2];
      float nv = cn * oc + cp * om + cq * op;
      stk_new[base] = nv;
      if (t == SEQn - 1)
        out[(size_t)SEQn * Bn * Hn + 2 * (size_t)Bn * Hn + base] = nv;
    }
    group_barrier(gbar, 32u * (uint32)(2 * t + 2));   // publish h, c-local, stack
  }
}

extern "C" void kernel_launch(void* const* d_in, const int* in_sizes, int n_in,
                              void* d_out, int out_size, void* d_ws, size_t ws_size,
                              hipStream_t stream) {
  (void)in_sizes; (void)n_in; (void)out_size; (void)ws_size;
  const float* x    = (const float*)d_in[0];
  const float* h0   = (const float*)d_in[1];
  const float* c0   = (const float*)d_in[2];
  const float* st0  = (const float*)d_in[3];
  const float* A_w  = (const float*)d_in[4];
  const float* A_b  = (const float*)d_in[5];
  const float* D_w  = (const float*)d_in[6];
  const float* D_b  = (const float*)d_in[7];
  const float* W_ih = (const float*)d_in[8];
  const float* W_hh = (const float*)d_in[9];
  const float* b_ih = (const float*)d_in[10];
  const float* b_hh = (const float*)d_in[11];

  char* ws = (char*)d_ws;
  unsigned short* ws_h = (unsigned short*)(ws);          // 256*512 bf16   = 262144 B
  float* ws_c = (float*)(ws + 262144);                   // 256*512 f32    = 524288 B
  float* ws_d = (float*)(ws + 786432);                   // 256*128 f32    = 131072 B
  uint32* bar = (uint32*)(ws + 917504);                  // 512 u32        = 2048 B
  float* stkA = (float*)(ws + 1048576);                  // 8 MiB
  float* stkB = (float*)(ws + 1048576 + 8388608);        // 8 MiB

  init_kernel<<<dim3(8192), dim3(256), 0, stream>>>(h0, c0, st0, ws_h, ws_c, stkA, bar);
  rnn_kernel<<<dim3(256), dim3(256), 0, stream>>>(
      x, A_w, A_b, D_w, D_b, W_ih, W_hh, b_ih, b_hh,
      (float*)d_out, ws_h, ws_c, ws_d, bar, stkA, stkB);
}